// Round 21
// baseline (38.788 us; speedup 1.0000x reference)
//
#include <hip/hip_runtime.h>

#define DEVI __device__ __forceinline__

typedef __attribute__((ext_vector_type(8)))  short s16x8;
typedef __attribute__((ext_vector_type(4)))  short s16x4;
typedef __attribute__((ext_vector_type(4)))  float f32x4;
typedef __attribute__((ext_vector_type(16))) float f32x16;
typedef __attribute__((ext_vector_type(2)))  unsigned u32x2;
typedef __attribute__((ext_vector_type(4)))  unsigned u32x4;

// float -> bf16 (RNE), bit pattern as short
DEVI short f2bf(float f) {
  unsigned u = __builtin_bit_cast(unsigned, f);
  u = u + 0x7fffu + ((u >> 16) & 1u);
  return (short)(u >> 16);
}
// two floats -> packed bf16 pair via HW cvt (RNE)
DEVI unsigned cvtpk(float lo, float hi) {
  unsigned r;
  asm("v_cvt_pk_bf16_f32 %0, %1, %2" : "=v"(r) : "v"(lo), "v"(hi));
  return r;
}
// async global->LDS 16B (no VGPR round-trip, deep queue)
DEVI void gll16(const short* g, short* l) {
  __builtin_amdgcn_global_load_lds(
      (const __attribute__((address_space(1))) unsigned*)g,
      (__attribute__((address_space(3))) unsigned*)l, 16, 0, 0);
}

constexpr int TT = 512;
constexpr int CC = 64;
constexpr float SCLQ = 0.18033688011112042f;  // log2(e)/8, folded into Q

// ---------------------------------------------------------------------------
// Kernel 1: QKV projections (r19 version, proven: inline weight convert,
// XCD-affinity decode).  Grid 1536; idx = xcd + 8*(tsr*64+(bn&7)*8+t8).
// ---------------------------------------------------------------------------
__global__ __launch_bounds__(256) void k_qkv(const float* __restrict__ values,
                                             const float* __restrict__ keys,
                                             const float* __restrict__ query,
                                             const float* __restrict__ Wq,
                                             const float* __restrict__ bq,
                                             const float* __restrict__ Wk,
                                             const float* __restrict__ bk,
                                             const float* __restrict__ Wv,
                                             short* __restrict__ qg,
                                             short* __restrict__ kg,
                                             short* __restrict__ vgT) {
  __shared__ __align__(16) short smem[16896];   // overlay: 33KB max
  short* lx = smem;                             // input tile (<=4224 shorts)
  const int idx = blockIdx.x;
  const int xcd = idx & 7, rest = idx >> 3;     // affinity decode
  const int tsr = rest >> 6;                    // 0=Q 1=K 2=V
  const int rr = rest & 63;
  const int bn = xcd * 8 + (rr >> 3), t8 = rr & 7;
  const int t0 = t8 * 64;
  const size_t xbase = (size_t)bn * TT * CC;
  const int tid = threadIdx.x;
  const int lane = tid & 63, w = tid >> 6;
  const int r = lane & 31, hl = lane >> 5;

  const float* in = (tsr == 0) ? query : (tsr == 1) ? keys : values;
  const int nrows = (tsr < 2) ? 66 : 64;
  const int halo = (tsr < 2) ? 2 : 0;
  short* lw = (tsr < 2) ? (smem + 4224) : (smem + 8320);
  short* lxT = smem + 4224;                     // V only

  // convert this block's weights fp32 -> bf16 into LDS
  if (tsr < 2) {
    const float* wsrc = tsr ? Wk : Wq;
    for (int s = tid; s < 4096; s += 256) {
      lw[s]        = f2bf(wsrc[s * 3 + 0]);
      lw[4096 + s] = f2bf(wsrc[s * 3 + 1]);
      lw[8192 + s] = f2bf(wsrc[s * 3 + 2]);
    }
  } else {
    for (int s = tid; s < 4096; s += 256) lw[s] = f2bf(Wv[s]);
  }

  // stage input rows [t0-halo, t0+64) as bf16, XOR-swizzled 128B rows
  for (int s = tid; s < nrows * 8; s += 256) {
    int row = s >> 3, c8 = s & 7;
    int t = t0 - halo + row;
    u32x4 rv;
    if (t >= 0) {
      const float4 a = *(const float4*)(in + xbase + (size_t)t * 64 + c8 * 8);
      const float4 b = *(const float4*)(in + xbase + (size_t)t * 64 + c8 * 8 + 4);
      rv[0] = cvtpk(a.x, a.y); rv[1] = cvtpk(a.z, a.w);
      rv[2] = cvtpk(b.x, b.y); rv[3] = cvtpk(b.z, b.w);
    } else {
      rv = (u32x4)(0u);
    }
    int byte = row * 128 + ((c8 * 16) ^ ((row & 7) << 4));
    *(u32x4*)((char*)lx + byte) = rv;
  }
  __syncthreads();

  // 4 jobs: mt(2) x nt(2); wave w takes job w
  {
    int mt = w >> 1, nt = w & 1;
    f32x16 acc;
#pragma unroll
    for (int i = 0; i < 16; ++i) acc[i] = 0.f;

    if (tsr < 2) {
#pragma unroll
      for (int kk = 0; kk < 3; ++kk) {
#pragma unroll
        for (int c4 = 0; c4 < 4; ++c4) {
          int lrow = mt * 32 + r + kk;
          int abyte = lrow * 128 + (((c4 * 16 + hl * 8) * 2) ^ ((lrow & 7) << 4));
          s16x8 af = *(const s16x8*)((const char*)lx + abyte);
          s16x8 bfr = *(const s16x8*)(lw + kk * 4096 + (nt * 32 + r) * 64 + c4 * 16 + hl * 8);
          acc = __builtin_amdgcn_mfma_f32_32x32x16_bf16(af, bfr, acc, 0, 0, 0);
        }
      }
    } else {
#pragma unroll
      for (int c4 = 0; c4 < 4; ++c4) {
        int lrow = mt * 32 + r;
        int abyte = lrow * 128 + (((c4 * 16 + hl * 8) * 2) ^ ((lrow & 7) << 4));
        s16x8 af = *(const s16x8*)((const char*)lx + abyte);
        s16x8 bfr = *(const s16x8*)(lw + (nt * 32 + r) * 64 + c4 * 16 + hl * 8);
        acc = __builtin_amdgcn_mfma_f32_32x32x16_bf16(af, bfr, acc, 0, 0, 0);
      }
    }
    int co = nt * 32 + r;
    if (tsr == 2) {
      // write transposed to LDS: lxT[co][t_local], XOR-swizzled 4-chunks
#pragma unroll
      for (int g2 = 0; g2 < 4; ++g2) {
        int tl = mt * 32 + g2 * 8 + hl * 4;
        u32x2 pk;
        pk[0] = cvtpk(acc[g2 * 4 + 0], acc[g2 * 4 + 1]);
        pk[1] = cvtpk(acc[g2 * 4 + 2], acc[g2 * 4 + 3]);
        *(u32x2*)(lxT + co * 64 + (tl ^ ((co & 15) << 2))) = pk;
      }
    } else {
      float bias = tsr ? bk[co] : bq[co];
      float scl = tsr ? 1.f : SCLQ;
      short* dst = tsr ? kg : qg;
#pragma unroll
      for (int reg = 0; reg < 16; ++reg) {
        int trow = mt * 32 + (reg & 3) + 8 * (reg >> 2) + 4 * hl;
        dst[((size_t)bn * TT + (t0 + trow)) * 64 + co] = f2bf((acc[reg] + bias) * scl);
      }
    }
  }
  if (tsr == 2) {
    __syncthreads();
    // coalesced copy-out: vgT[bn][co][t0 + t], 1024 chunks of 4 shorts
#pragma unroll
    for (int i = 0; i < 4; ++i) {
      int chunk = tid + 256 * i;
      int co = chunk >> 4, tc = chunk & 15;
      s16x4 v4 = *(const s16x4*)(lxT + co * 64 + ((tc * 4) ^ ((co & 15) << 2)));
      *(s16x4*)(vgT + ((size_t)bn * 64 + co) * TT + t0 + tc * 4) = v4;
    }
  }
}

// ---------------------------------------------------------------------------
// Kernel 2: attention — r20 body with Sums LDS ELIMINATED (denominator
// broadcast via __shfl(sum, qlocal): after the xor-32 reduce, every lane r
// holds q-col r's denominator).  LDS drops 33280 -> 32768B exactly ->
// 5 blocks/CU (was 4): 20 waves/CU, +25% TLP for a latency-bound loop
// (r11: VALUBusy 43%, Occupancy 41%).  K/V staged via gll (r20).
// Grid 1024 = (bn,h,qq); 4 waves, 1 mt/wave; (256,4) natural VGPR.
// ---------------------------------------------------------------------------
__global__ __launch_bounds__(256, 4) void k_attn(const short* __restrict__ qg,
                                                 const short* __restrict__ kg,
                                                 const short* __restrict__ vgT,
                                                 short* __restrict__ ag) {
  __shared__ __align__(16) short Kl[512 * 16];   // frag-major: tile nt at nt*512, lane*8
  __shared__ __align__(16) short Vl[16 * 512];   // [ch][t], 16B-granule XOR swizzle
  const int tid = threadIdx.x;
  // bijective XCD swizzle: all 16 (h,qq) blocks of one bn land on one XCD
  const int b = (blockIdx.x & 7) * 128 + (blockIdx.x >> 3);
  const int bn = b >> 4, h = (b >> 2) & 3, qq = b & 3;
  const int lane = tid & 63, w = tid >> 6;
  const int r = lane & 31, hl = lane >> 5;

  // stage K slice (512 x 16) into fragment-major LDS via gll
  const short* kslice = kg + (size_t)bn * TT * CC + h * 16;
#pragma unroll
  for (int j = 0; j < 4; ++j) {
    int g = j * 256 + tid;
    int nt = g >> 6, l = g & 63;
    gll16(kslice + (size_t)(nt * 32 + (l & 31)) * 64 + (l >> 5) * 8, Kl + g * 8);
  }
  // stage V slice (16 ch x 512 t) into LDS via gll (swizzle on source)
  const short* vslice = vgT + ((size_t)bn * 64 + h * 16) * TT;
#pragma unroll
  for (int j = 0; j < 4; ++j) {
    int d = j * 256 + tid;
    int ch = d >> 6, tc = (d & 63) ^ (ch & 7);
    gll16(vslice + (size_t)ch * TT + tc * 8, Vl + d * 8);
  }

  const int mt = qq * 4 + w;
  s16x8 qf = *(const s16x8*)(qg + ((size_t)bn * TT + mt * 32 + r) * CC + h * 16 + hl * 8);
  const int vch = r & 15;                         // lane's V channel (dups broadcast)
  const char* vrow = (const char*)Vl + vch * 1024;

  __syncthreads();   // drains vmcnt (gll) before LDS reads

  f32x16 z;
#pragma unroll
  for (int i = 0; i < 16; ++i) z[i] = 0.f;
  float sm0 = 0.f, sm1 = 0.f, sm2 = 0.f, sm3 = 0.f;
  f32x16 o;
#pragma unroll
  for (int i = 0; i < 16; ++i) o[i] = 0.f;

#pragma unroll
  for (int nt = 0; nt < 16; ++nt) {
    s16x8 kf = *(const s16x8*)(Kl + nt * 512 + lane * 8);
    f32x16 s = __builtin_amdgcn_mfma_f32_32x32x16_bf16(kf, qf, z, 0, 0, 0);
    float p[16];
#pragma unroll
    for (int i = 0; i < 16; ++i)
      p[i] = fmaxf(__builtin_amdgcn_exp2f(s[i]), 0.f);  // v_max shields asm consumer
#pragma unroll
    for (int i = 0; i < 4; ++i) {
      sm0 += p[4 * i + 0]; sm1 += p[4 * i + 1];
      sm2 += p[4 * i + 2]; sm3 += p[4 * i + 3];
    }
    unsigned pk[8];
#pragma unroll
    for (int m = 0; m < 8; ++m) pk[m] = cvtpk(p[2 * m], p[2 * m + 1]);
#pragma unroll
    for (int s2 = 0; s2 < 2; ++s2) {
      unsigned a0 = pk[4 * s2 + 0], b0 = pk[4 * s2 + 2];
      unsigned a1 = pk[4 * s2 + 1], b1 = pk[4 * s2 + 3];
      asm("v_permlane32_swap_b32 %0, %1" : "+v"(a0), "+v"(b0));
      asm("v_permlane32_swap_b32 %0, %1" : "+v"(a1), "+v"(b1));
      u32x4 fw; fw[0] = a0; fw[1] = a1; fw[2] = b0; fw[3] = b1;
      s16x8 fr = __builtin_bit_cast(s16x8, fw);
      s16x8 vf = *(const s16x8*)(vrow + (((nt * 32 + s2 * 16 + hl * 8) * 2) ^ ((vch & 7) << 4)));
      o = __builtin_amdgcn_mfma_f32_32x32x16_bf16(fr, vf, o, 0, 0, 0);
    }
  }
  float sum = (sm0 + sm1) + (sm2 + sm3);
  sum += __shfl_xor(sum, 32);
  // denominator broadcast in-register: lane qlocal holds q-col qlocal's sum
#pragma unroll
  for (int reg = 0; reg < 16; ++reg) {
    int qlocal = (reg & 3) + 8 * (reg >> 2) + 4 * hl;
    float sq = __shfl(sum, qlocal);
    if (r < 16) {
      float inv = __builtin_amdgcn_rcpf(sq);
      int q = mt * 32 + qlocal;
      ag[((size_t)bn * TT + q) * CC + h * 16 + r] = f2bf(o[reg] * inv);
    }
  }
}

// ---------------------------------------------------------------------------
// Kernel 3: final linear out = attn @ Wf^T + bf (fp32 out).  ag staged via
// gll (source absorbs swizzle); Wf converted in LDS.
// Grid 512 (64-row tiles), 1 job/wave + XCD-affinity decode (r17).
// ---------------------------------------------------------------------------
__global__ __launch_bounds__(256) void k_out(const short* __restrict__ ag,
                                             const float* __restrict__ Wf,
                                             const float* __restrict__ bfv,
                                             float* __restrict__ out) {
  __shared__ __align__(16) short la[64 * 64];
  __shared__ __align__(16) short lw[64 * 64];
  const int tid = threadIdx.x;
  const int xcd = blockIdx.x & 7, rest = blockIdx.x >> 3;  // affinity decode
  const int bn = xcd * 8 + (rest >> 3), t8 = rest & 7;
  const int t0 = t8 * 64;
  // ag staging via gll: granule d -> row d>>3, c8 = (d&7) ^ (row&7)
#pragma unroll
  for (int j = 0; j < 2; ++j) {
    int d = j * 256 + tid;
    int row = d >> 3, c8 = (d & 7) ^ (row & 7);
    gll16(ag + ((size_t)bn * TT + t0 + row) * 64 + c8 * 8, la + d * 8);
  }
  for (int s = tid; s < 4096; s += 256) lw[s] = f2bf(Wf[s]);
  __syncthreads();
  const int lane = tid & 63, w = tid >> 6;
  const int r = lane & 31, hl = lane >> 5;
  {
    int mt = w >> 1, nt = w & 1;
    f32x16 acc;
#pragma unroll
    for (int i = 0; i < 16; ++i) acc[i] = 0.f;
#pragma unroll
    for (int c4 = 0; c4 < 4; ++c4) {
      int lrow = mt * 32 + r;
      int abyte = lrow * 128 + (((c4 * 16 + hl * 8) * 2) ^ ((lrow & 7) << 4));
      s16x8 af = *(const s16x8*)((const char*)la + abyte);
      s16x8 bfr = *(const s16x8*)(lw + (nt * 32 + r) * 64 + c4 * 16 + hl * 8);
      acc = __builtin_amdgcn_mfma_f32_32x32x16_bf16(af, bfr, acc, 0, 0, 0);
    }
    int co = nt * 32 + r;
    float bias = bfv[co];
#pragma unroll
    for (int reg = 0; reg < 16; ++reg) {
      int trow = mt * 32 + (reg & 3) + 8 * (reg >> 2) + 4 * hl;
      out[((size_t)bn * TT + t0 + trow) * 64 + co] = acc[reg] + bias;
    }
  }
}

// ---------------------------------------------------------------------------
extern "C" void kernel_launch(void* const* d_in, const int* in_sizes, int n_in,
                              void* d_out, int out_size, void* d_ws, size_t ws_size,
                              hipStream_t stream) {
  const float* values = (const float*)d_in[0];
  const float* keys = (const float*)d_in[1];
  const float* query = (const float*)d_in[2];
  const float* Wq = (const float*)d_in[3];
  const float* bq = (const float*)d_in[4];
  const float* Wk = (const float*)d_in[5];
  const float* bk = (const float*)d_in[6];
  const float* Wv = (const float*)d_in[7];
  const float* Wf = (const float*)d_in[8];
  const float* bfv = (const float*)d_in[9];
  float* out = (float*)d_out;

  char* ws = (char*)d_ws;
  short* qg = (short*)ws;                               // 4 MiB each
  short* kg = (short*)(ws + (1 << 22));
  short* vgT = (short*)(ws + 2 * (1 << 22));
  short* ag = (short*)(ws + 3 * (size_t)(1 << 22));

  hipLaunchKernelGGL(k_qkv, dim3(1536), dim3(256), 0, stream,
                     values, keys, query, Wq, bq, Wk, bk, Wv, qg, kg, vgT);
  hipLaunchKernelGGL(k_attn, dim3(1024), dim3(256), 0, stream, qg, kg, vgT, ag);
  hipLaunchKernelGGL(k_out, dim3(512), dim3(256), 0, stream, ag, Wf, bfv, out);
}

// Round 22
// 38.467 us; speedup vs baseline: 1.0084x; 1.0084x over previous
//
#include <hip/hip_runtime.h>

#define DEVI __device__ __forceinline__

typedef __attribute__((ext_vector_type(8)))  short s16x8;
typedef __attribute__((ext_vector_type(4)))  short s16x4;
typedef __attribute__((ext_vector_type(4)))  float f32x4;
typedef __attribute__((ext_vector_type(16))) float f32x16;
typedef __attribute__((ext_vector_type(2)))  unsigned u32x2;
typedef __attribute__((ext_vector_type(4)))  unsigned u32x4;

// float -> bf16 (RNE), bit pattern as short
DEVI short f2bf(float f) {
  unsigned u = __builtin_bit_cast(unsigned, f);
  u = u + 0x7fffu + ((u >> 16) & 1u);
  return (short)(u >> 16);
}
// two floats -> packed bf16 pair via HW cvt (RNE)
DEVI unsigned cvtpk(float lo, float hi) {
  unsigned r;
  asm("v_cvt_pk_bf16_f32 %0, %1, %2" : "=v"(r) : "v"(lo), "v"(hi));
  return r;
}
// async global->LDS 16B (no VGPR round-trip, deep queue)
DEVI void gll16(const short* g, short* l) {
  __builtin_amdgcn_global_load_lds(
      (const __attribute__((address_space(1))) unsigned*)g,
      (__attribute__((address_space(3))) unsigned*)l, 16, 0, 0);
}

constexpr int TT = 512;
constexpr int CC = 64;
constexpr float SCLQ = 0.18033688011112042f;  // log2(e)/8, folded into Q

// ---------------------------------------------------------------------------
// Kernel 1: QKV projections (r19 body, affinity decode).  K written
// FRAGMENT-MAJOR per head (r18-verified): kgF[(bn*4+h)*8192 + (t>>5)*512 +
// (t&31)*8 + (ch>>3)*256 + (ch&7)] -> attn loads kf straight from global.
// Grid 1536; idx = xcd + 8*(tsr*64+(bn&7)*8+t8).
// ---------------------------------------------------------------------------
__global__ __launch_bounds__(256) void k_qkv(const float* __restrict__ values,
                                             const float* __restrict__ keys,
                                             const float* __restrict__ query,
                                             const float* __restrict__ Wq,
                                             const float* __restrict__ bq,
                                             const float* __restrict__ Wk,
                                             const float* __restrict__ bk,
                                             const float* __restrict__ Wv,
                                             short* __restrict__ qg,
                                             short* __restrict__ kgF,
                                             short* __restrict__ vgT) {
  __shared__ __align__(16) short smem[16896];   // overlay: 33KB max
  short* lx = smem;                             // input tile (<=4224 shorts)
  const int idx = blockIdx.x;
  const int xcd = idx & 7, rest = idx >> 3;     // affinity decode
  const int tsr = rest >> 6;                    // 0=Q 1=K 2=V
  const int rr = rest & 63;
  const int bn = xcd * 8 + (rr >> 3), t8 = rr & 7;
  const int t0 = t8 * 64;
  const size_t xbase = (size_t)bn * TT * CC;
  const int tid = threadIdx.x;
  const int lane = tid & 63, w = tid >> 6;
  const int r = lane & 31, hl = lane >> 5;

  const float* in = (tsr == 0) ? query : (tsr == 1) ? keys : values;
  const int nrows = (tsr < 2) ? 66 : 64;
  const int halo = (tsr < 2) ? 2 : 0;
  short* lw = (tsr < 2) ? (smem + 4224) : (smem + 8320);
  short* lxT = smem + 4224;                     // V only

  // convert this block's weights fp32 -> bf16 into LDS
  if (tsr < 2) {
    const float* wsrc = tsr ? Wk : Wq;
    for (int s = tid; s < 4096; s += 256) {
      lw[s]        = f2bf(wsrc[s * 3 + 0]);
      lw[4096 + s] = f2bf(wsrc[s * 3 + 1]);
      lw[8192 + s] = f2bf(wsrc[s * 3 + 2]);
    }
  } else {
    for (int s = tid; s < 4096; s += 256) lw[s] = f2bf(Wv[s]);
  }

  // stage input rows [t0-halo, t0+64) as bf16, XOR-swizzled 128B rows
  for (int s = tid; s < nrows * 8; s += 256) {
    int row = s >> 3, c8 = s & 7;
    int t = t0 - halo + row;
    u32x4 rv;
    if (t >= 0) {
      const float4 a = *(const float4*)(in + xbase + (size_t)t * 64 + c8 * 8);
      const float4 b = *(const float4*)(in + xbase + (size_t)t * 64 + c8 * 8 + 4);
      rv[0] = cvtpk(a.x, a.y); rv[1] = cvtpk(a.z, a.w);
      rv[2] = cvtpk(b.x, b.y); rv[3] = cvtpk(b.z, b.w);
    } else {
      rv = (u32x4)(0u);
    }
    int byte = row * 128 + ((c8 * 16) ^ ((row & 7) << 4));
    *(u32x4*)((char*)lx + byte) = rv;
  }
  __syncthreads();

  // 4 jobs: mt(2) x nt(2); wave w takes job w
  {
    int mt = w >> 1, nt = w & 1;
    f32x16 acc;
#pragma unroll
    for (int i = 0; i < 16; ++i) acc[i] = 0.f;

    if (tsr < 2) {
#pragma unroll
      for (int kk = 0; kk < 3; ++kk) {
#pragma unroll
        for (int c4 = 0; c4 < 4; ++c4) {
          int lrow = mt * 32 + r + kk;
          int abyte = lrow * 128 + (((c4 * 16 + hl * 8) * 2) ^ ((lrow & 7) << 4));
          s16x8 af = *(const s16x8*)((const char*)lx + abyte);
          s16x8 bfr = *(const s16x8*)(lw + kk * 4096 + (nt * 32 + r) * 64 + c4 * 16 + hl * 8);
          acc = __builtin_amdgcn_mfma_f32_32x32x16_bf16(af, bfr, acc, 0, 0, 0);
        }
      }
    } else {
#pragma unroll
      for (int c4 = 0; c4 < 4; ++c4) {
        int lrow = mt * 32 + r;
        int abyte = lrow * 128 + (((c4 * 16 + hl * 8) * 2) ^ ((lrow & 7) << 4));
        s16x8 af = *(const s16x8*)((const char*)lx + abyte);
        s16x8 bfr = *(const s16x8*)(lw + (nt * 32 + r) * 64 + c4 * 16 + hl * 8);
        acc = __builtin_amdgcn_mfma_f32_32x32x16_bf16(af, bfr, acc, 0, 0, 0);
      }
    }
    int co = nt * 32 + r;
    if (tsr == 2) {
      // write transposed to LDS: lxT[co][t_local], XOR-swizzled 4-chunks
#pragma unroll
      for (int g2 = 0; g2 < 4; ++g2) {
        int tl = mt * 32 + g2 * 8 + hl * 4;
        u32x2 pk;
        pk[0] = cvtpk(acc[g2 * 4 + 0], acc[g2 * 4 + 1]);
        pk[1] = cvtpk(acc[g2 * 4 + 2], acc[g2 * 4 + 3]);
        *(u32x2*)(lxT + co * 64 + (tl ^ ((co & 15) << 2))) = pk;
      }
    } else if (tsr == 0) {
      float bias = bq[co];
#pragma unroll
      for (int reg = 0; reg < 16; ++reg) {
        int trow = mt * 32 + (reg & 3) + 8 * (reg >> 2) + 4 * hl;
        qg[((size_t)bn * TT + (t0 + trow)) * 64 + co] = f2bf((acc[reg] + bias) * SCLQ);
      }
    } else {
      // K: fragment-major per head (h = co>>4, ch = co&15) — r18-verified
      float bias = bk[co];
      int h = co >> 4, ch = co & 15;
      short* kb = kgF + ((size_t)bn * 4 + h) * 8192 + (ch >> 3) * 256 + (ch & 7);
#pragma unroll
      for (int reg = 0; reg < 16; ++reg) {
        int t = t0 + mt * 32 + (reg & 3) + 8 * (reg >> 2) + 4 * hl;
        kb[(t >> 5) * 512 + (t & 31) * 8] = f2bf(acc[reg] + bias);
      }
    }
  }
  if (tsr == 2) {
    __syncthreads();
    // coalesced copy-out: vgT[bn][co][t0 + t], 1024 chunks of 4 shorts
#pragma unroll
    for (int i = 0; i < 4; ++i) {
      int chunk = tid + 256 * i;
      int co = chunk >> 4, tc = chunk & 15;
      s16x4 v4 = *(const s16x4*)(lxT + co * 64 + ((tc * 4) ^ ((co & 15) << 2)));
      *(s16x4*)(vgT + ((size_t)bn * 64 + co) * TT + t0 + tc * 4) = v4;
    }
  }
}

// ---------------------------------------------------------------------------
// Kernel 2: attention — K fragments from GLOBAL (frag-major kgF, one
// coalesced 16B/lane L2 load per nt); V via gll into LDS (r20); Sums-LDS
// epilogue (r20, measured best).  LDS 16.9KB -> 8-9 blocks/CU by LDS;
// NATURAL (256,4) bound (r18's (256,8) cap caused the VGPR-32 spill
// disaster — unbundled here).  If natural VGPR <=64 (r11 measured exactly
// 64): 32 waves/CU = 2x r20's TLP for the latency-bound chain.
// Grid 1024 = (bn,h,qq); 4 waves, 1 mt/wave.
// ---------------------------------------------------------------------------
__global__ __launch_bounds__(256, 4) void k_attn(const short* __restrict__ qg,
                                                 const short* __restrict__ kgF,
                                                 const short* __restrict__ vgT,
                                                 short* __restrict__ ag) {
  __shared__ __align__(16) short Vl[16 * 512];   // [ch][t], 16B-granule XOR swizzle
  __shared__ float Sums[4][32];
  const int tid = threadIdx.x;
  // bijective XCD swizzle: all 16 (h,qq) blocks of one bn land on one XCD
  const int b = (blockIdx.x & 7) * 128 + (blockIdx.x >> 3);
  const int bn = b >> 4, h = (b >> 2) & 3, qq = b & 3;
  const int lane = tid & 63, w = tid >> 6;
  const int r = lane & 31, hl = lane >> 5;

  // stage V slice (16 ch x 512 t) into LDS via gll (swizzle on source)
  const short* vslice = vgT + ((size_t)bn * 64 + h * 16) * TT;
#pragma unroll
  for (int j = 0; j < 4; ++j) {
    int d = j * 256 + tid;
    int ch = d >> 6, tc = (d & 63) ^ (ch & 7);
    gll16(vslice + (size_t)ch * TT + tc * 8, Vl + d * 8);
  }

  const int mt = qq * 4 + w;
  s16x8 qf = *(const s16x8*)(qg + ((size_t)bn * TT + mt * 32 + r) * CC + h * 16 + hl * 8);
  const short* kgh = kgF + ((size_t)bn * 4 + h) * 8192 + lane * 8;
  const int vch = r & 15;                         // lane's V channel (dups broadcast)
  const char* vrow = (const char*)Vl + vch * 1024;

  __syncthreads();   // drains vmcnt (gll) before LDS reads

  f32x16 z;
#pragma unroll
  for (int i = 0; i < 16; ++i) z[i] = 0.f;
  float sm0 = 0.f, sm1 = 0.f, sm2 = 0.f, sm3 = 0.f;
  f32x16 o;
#pragma unroll
  for (int i = 0; i < 16; ++i) o[i] = 0.f;

#pragma unroll
  for (int nt = 0; nt < 16; ++nt) {
    s16x8 kf = *(const s16x8*)(kgh + nt * 512);
    f32x16 s = __builtin_amdgcn_mfma_f32_32x32x16_bf16(kf, qf, z, 0, 0, 0);
    float p[16];
#pragma unroll
    for (int i = 0; i < 16; ++i)
      p[i] = fmaxf(__builtin_amdgcn_exp2f(s[i]), 0.f);  // v_max shields asm consumer
#pragma unroll
    for (int i = 0; i < 4; ++i) {
      sm0 += p[4 * i + 0]; sm1 += p[4 * i + 1];
      sm2 += p[4 * i + 2]; sm3 += p[4 * i + 3];
    }
    unsigned pk[8];
#pragma unroll
    for (int m = 0; m < 8; ++m) pk[m] = cvtpk(p[2 * m], p[2 * m + 1]);
#pragma unroll
    for (int s2 = 0; s2 < 2; ++s2) {
      unsigned a0 = pk[4 * s2 + 0], b0 = pk[4 * s2 + 2];
      unsigned a1 = pk[4 * s2 + 1], b1 = pk[4 * s2 + 3];
      asm("v_permlane32_swap_b32 %0, %1" : "+v"(a0), "+v"(b0));
      asm("v_permlane32_swap_b32 %0, %1" : "+v"(a1), "+v"(b1));
      u32x4 fw; fw[0] = a0; fw[1] = a1; fw[2] = b0; fw[3] = b1;
      s16x8 fr = __builtin_bit_cast(s16x8, fw);
      s16x8 vf = *(const s16x8*)(vrow + (((nt * 32 + s2 * 16 + hl * 8) * 2) ^ ((vch & 7) << 4)));
      o = __builtin_amdgcn_mfma_f32_32x32x16_bf16(fr, vf, o, 0, 0, 0);
    }
  }
  float sum = (sm0 + sm1) + (sm2 + sm3);
  sum += __shfl_xor(sum, 32);
  Sums[w][r] = sum;
  if (r < 16) {
#pragma unroll
    for (int reg = 0; reg < 16; ++reg) {
      int qlocal = (reg & 3) + 8 * (reg >> 2) + 4 * hl;
      float inv = __builtin_amdgcn_rcpf(Sums[w][qlocal]);
      int q = mt * 32 + qlocal;
      ag[((size_t)bn * TT + q) * CC + h * 16 + r] = f2bf(o[reg] * inv);
    }
  }
}

// ---------------------------------------------------------------------------
// Kernel 3: final linear out = attn @ Wf^T + bf (fp32 out).  ag staged via
// gll (source absorbs swizzle); Wf converted in LDS.
// Grid 512 (64-row tiles), 1 job/wave + XCD-affinity decode (r17).
// ---------------------------------------------------------------------------
__global__ __launch_bounds__(256) void k_out(const short* __restrict__ ag,
                                             const float* __restrict__ Wf,
                                             const float* __restrict__ bfv,
                                             float* __restrict__ out) {
  __shared__ __align__(16) short la[64 * 64];
  __shared__ __align__(16) short lw[64 * 64];
  const int tid = threadIdx.x;
  const int xcd = blockIdx.x & 7, rest = blockIdx.x >> 3;  // affinity decode
  const int bn = xcd * 8 + (rest >> 3), t8 = rest & 7;
  const int t0 = t8 * 64;
  // ag staging via gll: granule d -> row d>>3, c8 = (d&7) ^ (row&7)
#pragma unroll
  for (int j = 0; j < 2; ++j) {
    int d = j * 256 + tid;
    int row = d >> 3, c8 = (d & 7) ^ (row & 7);
    gll16(ag + ((size_t)bn * TT + t0 + row) * 64 + c8 * 8, la + d * 8);
  }
  for (int s = tid; s < 4096; s += 256) lw[s] = f2bf(Wf[s]);
  __syncthreads();
  const int lane = tid & 63, w = tid >> 6;
  const int r = lane & 31, hl = lane >> 5;
  {
    int mt = w >> 1, nt = w & 1;
    f32x16 acc;
#pragma unroll
    for (int i = 0; i < 16; ++i) acc[i] = 0.f;
#pragma unroll
    for (int c4 = 0; c4 < 4; ++c4) {
      int lrow = mt * 32 + r;
      int abyte = lrow * 128 + (((c4 * 16 + hl * 8) * 2) ^ ((lrow & 7) << 4));
      s16x8 af = *(const s16x8*)((const char*)la + abyte);
      s16x8 bfr = *(const s16x8*)(lw + (nt * 32 + r) * 64 + c4 * 16 + hl * 8);
      acc = __builtin_amdgcn_mfma_f32_32x32x16_bf16(af, bfr, acc, 0, 0, 0);
    }
    int co = nt * 32 + r;
    float bias = bfv[co];
#pragma unroll
    for (int reg = 0; reg < 16; ++reg) {
      int trow = mt * 32 + (reg & 3) + 8 * (reg >> 2) + 4 * hl;
      out[((size_t)bn * TT + t0 + trow) * 64 + co] = acc[reg] + bias;
    }
  }
}

// ---------------------------------------------------------------------------
extern "C" void kernel_launch(void* const* d_in, const int* in_sizes, int n_in,
                              void* d_out, int out_size, void* d_ws, size_t ws_size,
                              hipStream_t stream) {
  const float* values = (const float*)d_in[0];
  const float* keys = (const float*)d_in[1];
  const float* query = (const float*)d_in[2];
  const float* Wq = (const float*)d_in[3];
  const float* bq = (const float*)d_in[4];
  const float* Wk = (const float*)d_in[5];
  const float* bk = (const float*)d_in[6];
  const float* Wv = (const float*)d_in[7];
  const float* Wf = (const float*)d_in[8];
  const float* bfv = (const float*)d_in[9];
  float* out = (float*)d_out;

  char* ws = (char*)d_ws;
  short* qg = (short*)ws;                               // 4 MiB each
  short* kgF = (short*)(ws + (1 << 22));
  short* vgT = (short*)(ws + 2 * (1 << 22));
  short* ag = (short*)(ws + 3 * (size_t)(1 << 22));

  hipLaunchKernelGGL(k_qkv, dim3(1536), dim3(256), 0, stream,
                     values, keys, query, Wq, bq, Wk, bk, Wv, qg, kgF, vgT);
  hipLaunchKernelGGL(k_attn, dim3(1024), dim3(256), 0, stream, qg, kgF, vgT, ag);
  hipLaunchKernelGGL(k_out, dim3(512), dim3(256), 0, stream, ag, Wf, bfv, out);
}

// Round 23
// 34.938 us; speedup vs baseline: 1.1102x; 1.1010x over previous
//
#include <hip/hip_runtime.h>

#define DEVI __device__ __forceinline__

typedef __attribute__((ext_vector_type(8)))  short s16x8;
typedef __attribute__((ext_vector_type(4)))  short s16x4;
typedef __attribute__((ext_vector_type(4)))  float f32x4;
typedef __attribute__((ext_vector_type(16))) float f32x16;
typedef __attribute__((ext_vector_type(2)))  unsigned u32x2;
typedef __attribute__((ext_vector_type(4)))  unsigned u32x4;

// float -> bf16 (RNE), bit pattern as short
DEVI short f2bf(float f) {
  unsigned u = __builtin_bit_cast(unsigned, f);
  u = u + 0x7fffu + ((u >> 16) & 1u);
  return (short)(u >> 16);
}
// two floats -> packed bf16 pair via HW cvt (RNE)
DEVI unsigned cvtpk(float lo, float hi) {
  unsigned r;
  asm("v_cvt_pk_bf16_f32 %0, %1, %2" : "=v"(r) : "v"(lo), "v"(hi));
  return r;
}
// async global->LDS 16B (no VGPR round-trip, deep queue)
DEVI void gll16(const short* g, short* l) {
  __builtin_amdgcn_global_load_lds(
      (const __attribute__((address_space(1))) unsigned*)g,
      (__attribute__((address_space(3))) unsigned*)l, 16, 0, 0);
}

constexpr int TT = 512;
constexpr int CC = 64;
constexpr float SCLQ = 0.18033688011112042f;  // log2(e)/8, folded into Q

// ---------------------------------------------------------------------------
// Kernel 1: QKV projections (r22 version: inline weight convert, affinity
// decode, K written FRAGMENT-MAJOR per head for direct global kf loads).
// Grid 1536; idx = xcd + 8*(tsr*64+(bn&7)*8+t8).
// ---------------------------------------------------------------------------
__global__ __launch_bounds__(256) void k_qkv(const float* __restrict__ values,
                                             const float* __restrict__ keys,
                                             const float* __restrict__ query,
                                             const float* __restrict__ Wq,
                                             const float* __restrict__ bq,
                                             const float* __restrict__ Wk,
                                             const float* __restrict__ bk,
                                             const float* __restrict__ Wv,
                                             short* __restrict__ qg,
                                             short* __restrict__ kgF,
                                             short* __restrict__ vgT) {
  __shared__ __align__(16) short smem[16896];   // overlay: 33KB max
  short* lx = smem;                             // input tile (<=4224 shorts)
  const int idx = blockIdx.x;
  const int xcd = idx & 7, rest = idx >> 3;     // affinity decode
  const int tsr = rest >> 6;                    // 0=Q 1=K 2=V
  const int rr = rest & 63;
  const int bn = xcd * 8 + (rr >> 3), t8 = rr & 7;
  const int t0 = t8 * 64;
  const size_t xbase = (size_t)bn * TT * CC;
  const int tid = threadIdx.x;
  const int lane = tid & 63, w = tid >> 6;
  const int r = lane & 31, hl = lane >> 5;

  const float* in = (tsr == 0) ? query : (tsr == 1) ? keys : values;
  const int nrows = (tsr < 2) ? 66 : 64;
  const int halo = (tsr < 2) ? 2 : 0;
  short* lw = (tsr < 2) ? (smem + 4224) : (smem + 8320);
  short* lxT = smem + 4224;                     // V only

  // convert this block's weights fp32 -> bf16 into LDS
  if (tsr < 2) {
    const float* wsrc = tsr ? Wk : Wq;
    for (int s = tid; s < 4096; s += 256) {
      lw[s]        = f2bf(wsrc[s * 3 + 0]);
      lw[4096 + s] = f2bf(wsrc[s * 3 + 1]);
      lw[8192 + s] = f2bf(wsrc[s * 3 + 2]);
    }
  } else {
    for (int s = tid; s < 4096; s += 256) lw[s] = f2bf(Wv[s]);
  }

  // stage input rows [t0-halo, t0+64) as bf16, XOR-swizzled 128B rows
  for (int s = tid; s < nrows * 8; s += 256) {
    int row = s >> 3, c8 = s & 7;
    int t = t0 - halo + row;
    u32x4 rv;
    if (t >= 0) {
      const float4 a = *(const float4*)(in + xbase + (size_t)t * 64 + c8 * 8);
      const float4 b = *(const float4*)(in + xbase + (size_t)t * 64 + c8 * 8 + 4);
      rv[0] = cvtpk(a.x, a.y); rv[1] = cvtpk(a.z, a.w);
      rv[2] = cvtpk(b.x, b.y); rv[3] = cvtpk(b.z, b.w);
    } else {
      rv = (u32x4)(0u);
    }
    int byte = row * 128 + ((c8 * 16) ^ ((row & 7) << 4));
    *(u32x4*)((char*)lx + byte) = rv;
  }
  __syncthreads();

  // 4 jobs: mt(2) x nt(2); wave w takes job w
  {
    int mt = w >> 1, nt = w & 1;
    f32x16 acc;
#pragma unroll
    for (int i = 0; i < 16; ++i) acc[i] = 0.f;

    if (tsr < 2) {
#pragma unroll
      for (int kk = 0; kk < 3; ++kk) {
#pragma unroll
        for (int c4 = 0; c4 < 4; ++c4) {
          int lrow = mt * 32 + r + kk;
          int abyte = lrow * 128 + (((c4 * 16 + hl * 8) * 2) ^ ((lrow & 7) << 4));
          s16x8 af = *(const s16x8*)((const char*)lx + abyte);
          s16x8 bfr = *(const s16x8*)(lw + kk * 4096 + (nt * 32 + r) * 64 + c4 * 16 + hl * 8);
          acc = __builtin_amdgcn_mfma_f32_32x32x16_bf16(af, bfr, acc, 0, 0, 0);
        }
      }
    } else {
#pragma unroll
      for (int c4 = 0; c4 < 4; ++c4) {
        int lrow = mt * 32 + r;
        int abyte = lrow * 128 + (((c4 * 16 + hl * 8) * 2) ^ ((lrow & 7) << 4));
        s16x8 af = *(const s16x8*)((const char*)lx + abyte);
        s16x8 bfr = *(const s16x8*)(lw + (nt * 32 + r) * 64 + c4 * 16 + hl * 8);
        acc = __builtin_amdgcn_mfma_f32_32x32x16_bf16(af, bfr, acc, 0, 0, 0);
      }
    }
    int co = nt * 32 + r;
    if (tsr == 2) {
      // write transposed to LDS: lxT[co][t_local], XOR-swizzled 4-chunks
#pragma unroll
      for (int g2 = 0; g2 < 4; ++g2) {
        int tl = mt * 32 + g2 * 8 + hl * 4;
        u32x2 pk;
        pk[0] = cvtpk(acc[g2 * 4 + 0], acc[g2 * 4 + 1]);
        pk[1] = cvtpk(acc[g2 * 4 + 2], acc[g2 * 4 + 3]);
        *(u32x2*)(lxT + co * 64 + (tl ^ ((co & 15) << 2))) = pk;
      }
    } else if (tsr == 0) {
      float bias = bq[co];
#pragma unroll
      for (int reg = 0; reg < 16; ++reg) {
        int trow = mt * 32 + (reg & 3) + 8 * (reg >> 2) + 4 * hl;
        qg[((size_t)bn * TT + (t0 + trow)) * 64 + co] = f2bf((acc[reg] + bias) * SCLQ);
      }
    } else {
      // K: fragment-major per head (h = co>>4, ch = co&15) — r18/r22-verified
      float bias = bk[co];
      int h = co >> 4, ch = co & 15;
      short* kb = kgF + ((size_t)bn * 4 + h) * 8192 + (ch >> 3) * 256 + (ch & 7);
#pragma unroll
      for (int reg = 0; reg < 16; ++reg) {
        int t = t0 + mt * 32 + (reg & 3) + 8 * (reg >> 2) + 4 * hl;
        kb[(t >> 5) * 512 + (t & 31) * 8] = f2bf(acc[reg] + bias);
      }
    }
  }
  if (tsr == 2) {
    __syncthreads();
    // coalesced copy-out: vgT[bn][co][t0 + t], 1024 chunks of 4 shorts
#pragma unroll
    for (int i = 0; i < 4; ++i) {
      int chunk = tid + 256 * i;
      int co = chunk >> 4, tc = chunk & 15;
      s16x4 v4 = *(const s16x4*)(lxT + co * 64 + ((tc * 4) ^ ((co & 15) << 2)));
      *(s16x4*)(vgT + ((size_t)bn * 64 + co) * TT + t0 + tc * 4) = v4;
    }
  }
}

// ---------------------------------------------------------------------------
// Kernel 2: FUSED attention + output linear.  Grid 256 = (bn, qq of 128
// rows) x 1024 threads (16 waves).  Wave w16 runs the r20/r22 attn body for
// head h=w16&3, mt=qq*4+(w16>>2): K from global frag-major (kgF), V for all
// 4 heads staged via gll (64KB), output to LDS tile la (r4-validated
// layout).  After one sync, waves 0-7 apply Wf (bf16 in LDS) -> fp32 out.
// Saves: k_out launch+gap + 8MB ag global round-trip.  LDS 90KB ->
// 1 block/CU = 16 waves/CU (same TLP as r20's main loop).
// ---------------------------------------------------------------------------
__global__ __launch_bounds__(1024) void k_attn_out(const short* __restrict__ qg,
                                                   const short* __restrict__ kgF,
                                                   const short* __restrict__ vgT,
                                                   const float* __restrict__ Wf,
                                                   const float* __restrict__ bfv,
                                                   float* __restrict__ out) {
  __shared__ __align__(16) short Vl[64 * 512];   // [ch][t], 16B-granule XOR swizzle
  __shared__ __align__(16) short la[128 * 64];   // attn out tile, swizzled rows
  __shared__ __align__(16) short lw[64 * 64];    // Wf bf16
  __shared__ float Sums[16][32];
  const int tid = threadIdx.x;
  // affinity decode: bn on XCD bn>>3
  const int xcd = blockIdx.x & 7, rest = blockIdx.x >> 3;
  const int bn = xcd * 8 + (rest >> 2), qq = rest & 3;
  const int lane = tid & 63, w16 = tid >> 6;
  const int h = w16 & 3, mtl = w16 >> 2;
  const int r = lane & 31, hl = lane >> 5;

  // stage full V slice (64 ch x 512 t) via gll (swizzle on source)
  const short* vslice = vgT + (size_t)bn * 64 * TT;
#pragma unroll
  for (int j = 0; j < 4; ++j) {
    int d = j * 1024 + tid;
    int ch = d >> 6, tc = (d & 63) ^ (ch & 7);
    gll16(vslice + (size_t)ch * TT + tc * 8, Vl + d * 8);
  }
  // convert Wf fp32 -> bf16 into LDS
  for (int s = tid; s < 4096; s += 1024) lw[s] = f2bf(Wf[s]);

  const int mt = qq * 4 + mtl;
  s16x8 qf = *(const s16x8*)(qg + ((size_t)bn * TT + mt * 32 + r) * CC + h * 16 + hl * 8);
  const short* kgh = kgF + ((size_t)bn * 4 + h) * 8192 + lane * 8;
  const int vch = h * 16 + (r & 15);              // lane's V channel (dups broadcast)
  const char* vrow = (const char*)Vl + vch * 1024;

  __syncthreads();   // drains vmcnt (gll) before LDS reads

  f32x16 z;
#pragma unroll
  for (int i = 0; i < 16; ++i) z[i] = 0.f;
  float sm0 = 0.f, sm1 = 0.f, sm2 = 0.f, sm3 = 0.f;
  f32x16 o;
#pragma unroll
  for (int i = 0; i < 16; ++i) o[i] = 0.f;

#pragma unroll
  for (int nt = 0; nt < 16; ++nt) {
    s16x8 kf = *(const s16x8*)(kgh + nt * 512);
    f32x16 s = __builtin_amdgcn_mfma_f32_32x32x16_bf16(kf, qf, z, 0, 0, 0);
    float p[16];
#pragma unroll
    for (int i = 0; i < 16; ++i)
      p[i] = fmaxf(__builtin_amdgcn_exp2f(s[i]), 0.f);  // v_max shields asm consumer
#pragma unroll
    for (int i = 0; i < 4; ++i) {
      sm0 += p[4 * i + 0]; sm1 += p[4 * i + 1];
      sm2 += p[4 * i + 2]; sm3 += p[4 * i + 3];
    }
    unsigned pk[8];
#pragma unroll
    for (int m = 0; m < 8; ++m) pk[m] = cvtpk(p[2 * m], p[2 * m + 1]);
#pragma unroll
    for (int s2 = 0; s2 < 2; ++s2) {
      unsigned a0 = pk[4 * s2 + 0], b0 = pk[4 * s2 + 2];
      unsigned a1 = pk[4 * s2 + 1], b1 = pk[4 * s2 + 3];
      asm("v_permlane32_swap_b32 %0, %1" : "+v"(a0), "+v"(b0));
      asm("v_permlane32_swap_b32 %0, %1" : "+v"(a1), "+v"(b1));
      u32x4 fw; fw[0] = a0; fw[1] = a1; fw[2] = b0; fw[3] = b1;
      s16x8 fr = __builtin_bit_cast(s16x8, fw);
      s16x8 vf = *(const s16x8*)(vrow + (((nt * 32 + s2 * 16 + hl * 8) * 2) ^ ((vch & 7) << 4)));
      o = __builtin_amdgcn_mfma_f32_32x32x16_bf16(fr, vf, o, 0, 0, 0);
    }
  }
  float sum = (sm0 + sm1) + (sm2 + sm3);
  sum += __shfl_xor(sum, 32);
  Sums[w16][r] = sum;
  if (r < 16) {
#pragma unroll
    for (int reg = 0; reg < 16; ++reg) {
      int qlocal = (reg & 3) + 8 * (reg >> 2) + 4 * hl;
      float inv = __builtin_amdgcn_rcpf(Sums[w16][qlocal]);
      int row = mtl * 32 + qlocal;
      int col = h * 16 + r;
      *(short*)((char*)la + row * 128 + (((col >> 3) * 16) ^ ((row & 7) << 4)) + (col & 7) * 2) =
          f2bf(o[reg] * inv);
    }
  }
  __syncthreads();

  // output linear: waves 0..7 do 8 jobs (mt2 x nt); rows qq*128..+128
  if (w16 < 8) {
    int mt2 = w16 >> 1, nt = w16 & 1;
    f32x16 acc;
#pragma unroll
    for (int i = 0; i < 16; ++i) acc[i] = 0.f;
#pragma unroll
    for (int c4 = 0; c4 < 4; ++c4) {
      int lrow = mt2 * 32 + r;
      int abyte = lrow * 128 + (((c4 * 16 + hl * 8) * 2) ^ ((lrow & 7) << 4));
      s16x8 af = *(const s16x8*)((const char*)la + abyte);
      s16x8 bfr = *(const s16x8*)(lw + (nt * 32 + r) * 64 + c4 * 16 + hl * 8);
      acc = __builtin_amdgcn_mfma_f32_32x32x16_bf16(af, bfr, acc, 0, 0, 0);
    }
    int co = nt * 32 + r;
    float bias = bfv[co];
#pragma unroll
    for (int reg = 0; reg < 16; ++reg) {
      int trow = mt2 * 32 + (reg & 3) + 8 * (reg >> 2) + 4 * hl;
      out[((size_t)bn * TT + qq * 128 + trow) * CC + co] = acc[reg] + bias;
    }
  }
}

// ---------------------------------------------------------------------------
extern "C" void kernel_launch(void* const* d_in, const int* in_sizes, int n_in,
                              void* d_out, int out_size, void* d_ws, size_t ws_size,
                              hipStream_t stream) {
  const float* values = (const float*)d_in[0];
  const float* keys = (const float*)d_in[1];
  const float* query = (const float*)d_in[2];
  const float* Wq = (const float*)d_in[3];
  const float* bq = (const float*)d_in[4];
  const float* Wk = (const float*)d_in[5];
  const float* bk = (const float*)d_in[6];
  const float* Wv = (const float*)d_in[7];
  const float* Wf = (const float*)d_in[8];
  const float* bfv = (const float*)d_in[9];
  float* out = (float*)d_out;

  char* ws = (char*)d_ws;
  short* qg = (short*)ws;                               // 4 MiB each
  short* kgF = (short*)(ws + (1 << 22));
  short* vgT = (short*)(ws + 2 * (1 << 22));

  hipLaunchKernelGGL(k_qkv, dim3(1536), dim3(256), 0, stream,
                     values, keys, query, Wq, bq, Wk, bk, Wv, qg, kgF, vgT);
  hipLaunchKernelGGL(k_attn_out, dim3(256), dim3(1024), 0, stream,
                     qg, kgF, vgT, Wf, bfv, out);
}